// Round 1
// baseline (74.638 us; speedup 1.0000x reference)
//
#include <hip/hip_runtime.h>
#include <hip/hip_bf16.h>

#define DEVI static __device__ __forceinline__

typedef __attribute__((ext_vector_type(8))) short short8;
typedef __attribute__((ext_vector_type(16))) float f32x16;

#define S_LEN 2048
#define D_DIM 128
#define NBATCH 16
#define QK_SCALE 0.08838834764831845f  // 1/sqrt(128)

DEVI unsigned short f2bf(float x) {
  union { float f; unsigned int u; } a; a.f = x;
  unsigned int u = a.u;
  unsigned int r = (u + 0x7fffu + ((u >> 16) & 1u)) >> 16;
  return (unsigned short)r;
}

DEVI unsigned int packbf(float lo, float hi) {
  return (unsigned int)f2bf(lo) | ((unsigned int)f2bf(hi) << 16);
}

// ---------------- prepass kernels ----------------

__global__ void cvtqk(const float* __restrict__ Q, const float* __restrict__ K,
                      unsigned short* __restrict__ Qb, unsigned short* __restrict__ Kb) {
  const int M4 = (NBATCH * S_LEN * D_DIM) / 4;
  for (int i = blockIdx.x * blockDim.x + threadIdx.x; i < 2 * M4;
       i += gridDim.x * blockDim.x) {
    const int t = (i >= M4) ? 1 : 0;
    const size_t idx = (size_t)(t ? (i - M4) : i) * 4;
    const float4 v = *reinterpret_cast<const float4*>((t ? K : Q) + idx);
    ushort4 o;
    o.x = f2bf(v.x); o.y = f2bf(v.y); o.z = f2bf(v.z); o.w = f2bf(v.w);
    *reinterpret_cast<ushort4*>((t ? Kb : Qb) + idx) = o;
  }
}

// V [b][s][d] fp32 -> Vt [b][d][s] bf16
__global__ void vtrans(const float* __restrict__ V, unsigned short* __restrict__ Vt) {
  __shared__ unsigned short t[64][68];
  const int bid = blockIdx.x;
  const int b = bid >> 6, rem = bid & 63;
  const int s0 = (rem & 31) * 64, d0 = (rem >> 5) * 64;
  const int tt = threadIdx.x;
  const int r = tt >> 2, c = (tt & 3) * 16;
  const float* src = V + ((size_t)(b * S_LEN + s0 + r)) * D_DIM + d0 + c;
#pragma unroll
  for (int i = 0; i < 4; i++) {
    float4 v = reinterpret_cast<const float4*>(src)[i];
    t[r][c + 4 * i + 0] = f2bf(v.x);
    t[r][c + 4 * i + 1] = f2bf(v.y);
    t[r][c + 4 * i + 2] = f2bf(v.z);
    t[r][c + 4 * i + 3] = f2bf(v.w);
  }
  __syncthreads();
  unsigned short* dst = Vt + ((size_t)(b * D_DIM + d0 + r)) * S_LEN + s0 + c;
#pragma unroll
  for (int i = 0; i < 4; i++) {
    ushort4 o;
    o.x = t[c + 4 * i + 0][r];
    o.y = t[c + 4 * i + 1][r];
    o.z = t[c + 4 * i + 2][r];
    o.w = t[c + 4 * i + 3][r];
    reinterpret_cast<ushort4*>(dst)[i] = o;
  }
}

// Tsum[b][t][d] = sum of V rows in 64-row tile t
__global__ void sufA(const float* __restrict__ V, float* __restrict__ Tsum) {
  const int bid = blockIdx.x;  // b*32 + t
  const int d = threadIdx.x;
  const float* p = V + ((size_t)bid * 64) * D_DIM + d;
  float s = 0.0f;
#pragma unroll 8
  for (int k = 0; k < 64; k++) s += p[(size_t)k * D_DIM];
  Tsum[(size_t)bid * D_DIM + d] = s;
}

// SufV[b][t][d] = sum_{t' >= t} Tsum[b][t'][d]; SufV[b][32][d] = 0
__global__ void sufB(const float* __restrict__ Tsum, float* __restrict__ SufV) {
  const int b = blockIdx.x;
  const int d = threadIdx.x;
  float run = 0.0f;
  SufV[((size_t)b * 33 + 32) * 128 + d] = 0.0f;
  for (int t = 31; t >= 0; t--) {
    run += Tsum[((size_t)b * 32 + t) * 128 + d];
    SufV[((size_t)b * 33 + t) * 128 + d] = run;
  }
}

// ---------------- attention kernel ----------------

DEVI void stage_tiles(char* ldsK, char* ldsV, const unsigned short* Kb,
                      const unsigned short* Vt, int b, int kt, int w, int lane) {
  const int kv0 = kt * 64;
  if (w < 2) {
    // K tile: 64 rows x 256B, contiguous in global; XOR-swizzle via pre-swizzled source
    const char* ktile = (const char*)(Kb + ((size_t)b * S_LEN + kv0) * D_DIM);
#pragma unroll
    for (int i = 0; i < 8; i++) {
      int c = w * 8 + i;
      int L = c * 1024 + lane * 16;
      int row = L >> 8;
      int src = row * 256 + ((L & 255) ^ ((row & 7) << 4));
      __builtin_amdgcn_global_load_lds(
          (const __attribute__((address_space(1))) unsigned int*)(ktile + src),
          (__attribute__((address_space(3))) unsigned int*)(ldsK + c * 1024),
          16, 0, 0);
    }
  } else {
    // V^T tile: 128 rows x 128B, row stride S*2 in global
#pragma unroll
    for (int i = 0; i < 8; i++) {
      int c = (w - 2) * 8 + i;
      int L = c * 1024 + lane * 16;
      int row = L >> 7;
      int xs = (L & 127) ^ ((row & 7) << 4);
      const char* src = (const char*)Vt +
                        (((size_t)b * D_DIM + row) * S_LEN + kv0) * 2 + xs;
      __builtin_amdgcn_global_load_lds(
          (const __attribute__((address_space(1))) unsigned int*)src,
          (__attribute__((address_space(3))) unsigned int*)(ldsV + c * 1024),
          16, 0, 0);
    }
  }
}

DEVI short8 ldK(const char* ldsK, int row, int off) {
  int addr = row * 256 + (off ^ ((row & 7) << 4));
  return *reinterpret_cast<const short8*>(ldsK + addr);
}
DEVI short8 ldV(const char* ldsV, int row, int off) {
  int addr = row * 128 + (off ^ ((row & 7) << 4));
  return *reinterpret_cast<const short8*>(ldsV + addr);
}

__global__ __launch_bounds__(256, 2) void attn_kernel(
    const unsigned short* __restrict__ Qb, const unsigned short* __restrict__ Kb,
    const unsigned short* __restrict__ Vt, const float* __restrict__ SufV,
    float* __restrict__ out) {
  __shared__ __align__(16) char smem[2][32768];  // per buf: K tile @0 (16KB), V^T tile @16KB

  const int tid = threadIdx.x;
  const int w = tid >> 6, lane = tid & 63;
  const int ln31 = lane & 31, h = lane >> 5;
  const int qs = w & 1;   // q half: rows [q0+32*qs, +32)
  const int kh = w >> 1;  // kv half of each 64-tile

  // dispatch swizzle: XCD-local batches + (j, 31-j) CU pairing
  const int bid = blockIdx.x;
  const int x = bid & 7, s = bid >> 3;
  const int b = 2 * x + (s & 1);
  const int sh = s >> 1;
  const int j = (s < 32) ? sh : (47 - sh);
  const int q0 = j * 64;
  const int nkt = j + 1;
  const int kv_end = q0 + 64;
  const int qrow = q0 + 32 * qs + ln31;

  // Q fragments (B-operand): frag kf element jj <-> d = 16*kf + 8*h + jj
  short8 qf[8];
  {
    const unsigned short* qbase = Qb + ((size_t)b * S_LEN + qrow) * D_DIM + 8 * h;
#pragma unroll
    for (int kf = 0; kf < 8; kf++)
      qf[kf] = *reinterpret_cast<const short8*>(qbase + 16 * kf);
  }

  f32x16 acc[4];
#pragma unroll
  for (int nt = 0; nt < 4; nt++)
#pragma unroll
    for (int r = 0; r < 16; r++) acc[nt][r] = 0.0f;

  float m_run = 0.0f, l_run = 0.0f;  // m starts at 0: masked zeros are in the softmax

  stage_tiles(smem[0], smem[0] + 16384, Kb, Vt, b, 0, w, lane);
  __syncthreads();

  for (int kt = 0; kt < nkt; kt++) {
    char* cb = smem[kt & 1];
    if (kt + 1 < nkt)
      stage_tiles(smem[(kt + 1) & 1], smem[(kt + 1) & 1] + 16384, Kb, Vt, b,
                  kt + 1, w, lane);

    // S^T = K_half * Q^T  (swapped operands: lane owns one q column)
    f32x16 sT;
#pragma unroll
    for (int r = 0; r < 16; r++) sT[r] = 0.0f;
#pragma unroll
    for (int kf = 0; kf < 8; kf++) {
      short8 af = ldK(cb, ln31 + 32 * kh, 32 * kf + 16 * h);
      sT = __builtin_amdgcn_mfma_f32_32x32x16_bf16(af, qf[kf], sT, 0, 0, 0);
    }

    // scale + multiplicative mask (score := 0 above diagonal)
    const int kvb = kt * 64 + 32 * kh;
#pragma unroll
    for (int r = 0; r < 16; r++) {
      float v = sT[r] * QK_SCALE;
      int kvg = kvb + (r & 3) + 8 * (r >> 2) + 4 * h;
      sT[r] = (kvg > qrow) ? 0.0f : v;
    }

    // row max: 16 in-lane + one cross-half exchange
    float tm[8];
#pragma unroll
    for (int r = 0; r < 8; r++) tm[r] = fmaxf(sT[r], sT[r + 8]);
#pragma unroll
    for (int r = 0; r < 4; r++) tm[r] = fmaxf(tm[r], tm[r + 4]);
    float mx = fmaxf(fmaxf(tm[0], tm[2]), fmaxf(tm[1], tm[3]));
    mx = fmaxf(mx, __shfl_xor(mx, 32));
    float mnew = fmaxf(m_run, mx);
    float alpha = __expf(m_run - mnew);
    m_run = mnew;

    // exp + row sum
#pragma unroll
    for (int r = 0; r < 16; r++) sT[r] = __expf(sT[r] - mnew);
    float ts[8];
#pragma unroll
    for (int r = 0; r < 8; r++) ts[r] = sT[r] + sT[r + 8];
#pragma unroll
    for (int r = 0; r < 4; r++) ts[r] = ts[r] + ts[r + 4];
    float sum = (ts[0] + ts[1]) + (ts[2] + ts[3]);
    sum += __shfl_xor(sum, 32);
    l_run = l_run * alpha + sum;

    // rescale accumulator (alpha indexed by output row = crow(r,h))
    float ar[16];
#pragma unroll
    for (int r = 0; r < 16; r++)
      ar[r] = __shfl(alpha, (r & 3) + 8 * (r >> 2) + 4 * h);
#pragma unroll
    for (int nt = 0; nt < 4; nt++)
#pragma unroll
      for (int r = 0; r < 16; r++) acc[nt][r] *= ar[r];

    // pack P -> bf16 A-fragments (16 cvt-pk + cross-half exchange), then PV
#pragma unroll
    for (int kl = 0; kl < 2; kl++) {
      const int r2a = (2 * kl) & 3;      // receiver h = 0
      const int r2b = (2 * kl + 1) & 3;  // receiver h = 1
      float l0lo = h ? sT[0 + 4 * r2b] : sT[0 + 4 * r2a];
      float l0hi = h ? sT[1 + 4 * r2b] : sT[1 + 4 * r2a];
      float l1lo = h ? sT[2 + 4 * r2b] : sT[2 + 4 * r2a];
      float l1hi = h ? sT[3 + 4 * r2b] : sT[3 + 4 * r2a];
      float s0lo = h ? sT[0 + 4 * r2a] : sT[0 + 4 * r2b];
      float s0hi = h ? sT[1 + 4 * r2a] : sT[1 + 4 * r2b];
      float s1lo = h ? sT[2 + 4 * r2a] : sT[2 + 4 * r2b];
      float s1hi = h ? sT[3 + 4 * r2a] : sT[3 + 4 * r2b];
      unsigned int uloc0 = packbf(l0lo, l0hi), uloc1 = packbf(l1lo, l1hi);
      unsigned int usnd0 = packbf(s0lo, s0hi), usnd1 = packbf(s1lo, s1hi);
      unsigned int urcv0 = (unsigned int)__shfl_xor((int)usnd0, 32);
      unsigned int urcv1 = (unsigned int)__shfl_xor((int)usnd1, 32);
      union { short8 v; unsigned int u[4]; } pa;
      pa.u[0] = h ? urcv0 : uloc0;
      pa.u[1] = h ? urcv1 : uloc1;
      pa.u[2] = h ? uloc0 : urcv0;
      pa.u[3] = h ? uloc1 : urcv1;
      const int vboff = 64 * kh + 32 * kl + 16 * h;
#pragma unroll
      for (int nt = 0; nt < 4; nt++) {
        short8 vb = ldV(cb + 16384, ln31 + 32 * nt, vboff);
        acc[nt] = __builtin_amdgcn_mfma_f32_32x32x16_bf16(pa.v, vb, acc[nt], 0, 0, 0);
      }
    }
    __syncthreads();
  }

  // merge kv halves (disjoint key sets) + masked-tail correction + write
  float* mb = (float*)smem;  // [2][64][68] floats, reuses tile LDS
  if (kh == 1) {
    float* p = mb + (size_t)(qs * 64 + lane) * 68;
#pragma unroll
    for (int nt = 0; nt < 4; nt++)
#pragma unroll
      for (int r = 0; r < 16; r++) p[nt * 16 + r] = acc[nt][r];
    p[64] = m_run;
    p[65] = l_run;
  }
  __syncthreads();
  if (kh == 0) {
    const float* p = mb + (size_t)(qs * 64 + lane) * 68;
    float m1 = p[64], l1 = p[65];
    float m12 = fmaxf(m_run, m1);
    float b0 = __expf(m_run - m12);
    float b1 = __expf(m1 - m12);
    float l12 = l_run * b0 + l1 * b1;
    float e = __expf(-m12);  // weight of each fully-masked (score 0) position
    l12 += (float)(S_LEN - kv_end) * e;
    float b0r[16], b1r[16], er[16], lr[16];
#pragma unroll
    for (int r = 0; r < 16; r++) {
      int cr = (r & 3) + 8 * (r >> 2) + 4 * h;
      b0r[r] = __shfl(b0, cr);
      b1r[r] = __shfl(b1, cr);
      er[r] = __shfl(e, cr);
      lr[r] = __shfl(l12, cr);
    }
    const float* sv = SufV + ((size_t)b * 33 + (kv_end >> 6)) * 128;
    float* ob = out + ((size_t)b * S_LEN + q0 + 32 * qs) * D_DIM + ln31;
#pragma unroll
    for (int nt = 0; nt < 4; nt++) {
      float svv = sv[ln31 + 32 * nt];
#pragma unroll
      for (int r = 0; r < 16; r++) {
        int cr = (r & 3) + 8 * (r >> 2) + 4 * h;
        float o = acc[nt][r] * b0r[r] + p[nt * 16 + r] * b1r[r] + er[r] * svv;
        ob[(size_t)cr * D_DIM + 32 * nt] = o / lr[r];
      }
    }
  }
}

// ---------------- launcher ----------------

extern "C" void kernel_launch(void* const* d_in, const int* in_sizes, int n_in,
                              void* d_out, int out_size, void* d_ws, size_t ws_size,
                              hipStream_t stream) {
  const float* Q = (const float*)d_in[0];
  const float* K = (const float*)d_in[1];
  const float* V = (const float*)d_in[2];
  float* out = (float*)d_out;

  char* ws = (char*)d_ws;
  unsigned short* Qb = (unsigned short*)ws;                 // 8 MiB
  unsigned short* Kb = Qb + 4194304;                        // 8 MiB
  unsigned short* Vt = Kb + 4194304;                        // 8 MiB
  float* Tsum = (float*)(ws + 25165824);                    // 256 KiB
  float* SufV = Tsum + 65536;                               // 264 KiB

  cvtqk<<<2048, 256, 0, stream>>>(Q, K, Qb, Kb);
  vtrans<<<1024, 256, 0, stream>>>(V, Vt);
  sufA<<<512, 128, 0, stream>>>(V, Tsum);
  sufB<<<16, 128, 0, stream>>>(Tsum, SufV);
  attn_kernel<<<512, 256, 0, stream>>>(Qb, Kb, Vt, SufV, out);
}

// Round 2
// 64.785 us; speedup vs baseline: 1.1521x; 1.1521x over previous
//
#include <hip/hip_runtime.h>
#include <hip/hip_bf16.h>

#define DEVI static __device__ __forceinline__

typedef __attribute__((ext_vector_type(8))) short short8;
typedef __attribute__((ext_vector_type(16))) float f32x16;

#define S_LEN 2048
#define D_DIM 128
#define NBATCH 16
// (1/sqrt(128)) * log2(e): base-2 softmax, scale folded into Q conversion
#define QSC ((float)(0.08838834764831845 * 1.4426950408889634))

#if __has_builtin(__builtin_amdgcn_exp2f)
#define EXP2(x) __builtin_amdgcn_exp2f(x)
#else
#define EXP2(x) exp2f(x)
#endif

DEVI unsigned short f2bf(float x) {
  union { float f; unsigned int u; } a; a.f = x;
  unsigned int u = a.u;
  unsigned int r = (u + 0x7fffu + ((u >> 16) & 1u)) >> 16;
  return (unsigned short)r;
}

DEVI unsigned int cvtpk(float lo, float hi) {
  unsigned int r;
  asm volatile("v_cvt_pk_bf16_f32 %0, %1, %2" : "=v"(r) : "v"(lo), "v"(hi));
  return r;
}

// ---------------- prepass kernels ----------------

__global__ void cvtk(const float* __restrict__ K, unsigned short* __restrict__ Kb) {
  const int M4 = (NBATCH * S_LEN * D_DIM) / 4;
  for (int i = blockIdx.x * blockDim.x + threadIdx.x; i < M4;
       i += gridDim.x * blockDim.x) {
    const size_t idx = (size_t)i * 4;
    const float4 v = *reinterpret_cast<const float4*>(K + idx);
    ushort4 o;
    o.x = f2bf(v.x); o.y = f2bf(v.y); o.z = f2bf(v.z); o.w = f2bf(v.w);
    *reinterpret_cast<ushort4*>(Kb + idx) = o;
  }
}

// V [b][s][d] fp32 -> Vt [b][d][s] bf16, fused with per-64-row-tile column sums
__global__ void vtrans(const float* __restrict__ V, unsigned short* __restrict__ Vt,
                       float* __restrict__ Tsum) {
  __shared__ unsigned short t[64][68];
  const int bid = blockIdx.x;
  const int b = bid >> 6, rem = bid & 63;
  const int st = rem & 31, s0 = st * 64, d0 = (rem >> 5) * 64;
  const int tt = threadIdx.x;
  const int r = tt >> 2, c = (tt & 3) * 16;
  const float* src = V + ((size_t)(b * S_LEN + s0 + r)) * D_DIM + d0 + c;
#pragma unroll
  for (int i = 0; i < 4; i++) {
    float4 v = reinterpret_cast<const float4*>(src)[i];
    t[r][c + 4 * i + 0] = f2bf(v.x);
    t[r][c + 4 * i + 1] = f2bf(v.y);
    t[r][c + 4 * i + 2] = f2bf(v.z);
    t[r][c + 4 * i + 3] = f2bf(v.w);
  }
  __syncthreads();
  unsigned short* dst = Vt + ((size_t)(b * D_DIM + d0 + r)) * S_LEN + s0 + c;
#pragma unroll
  for (int i = 0; i < 4; i++) {
    ushort4 o;
    o.x = t[c + 4 * i + 0][r];
    o.y = t[c + 4 * i + 1][r];
    o.z = t[c + 4 * i + 2][r];
    o.w = t[c + 4 * i + 3][r];
    reinterpret_cast<ushort4*>(dst)[i] = o;
  }
  if (tt < 64) {
    float s = 0.0f;
#pragma unroll 8
    for (int rr = 0; rr < 64; rr++) {
      union { float f; unsigned int u; } cv;
      cv.u = ((unsigned int)t[rr][tt]) << 16;
      s += cv.f;
    }
    Tsum[((size_t)b * 32 + st) * 128 + d0 + tt] = s;
  }
}

// SufV[b][t][d] = sum_{t' >= t} Tsum[b][t'][d]; SufV[b][32][d] = 0
__global__ void sufB(const float* __restrict__ Tsum, float* __restrict__ SufV) {
  const int b = blockIdx.x;
  const int d = threadIdx.x;
  float run = 0.0f;
  SufV[((size_t)b * 33 + 32) * 128 + d] = 0.0f;
  for (int t = 31; t >= 0; t--) {
    run += Tsum[((size_t)b * 32 + t) * 128 + d];
    SufV[((size_t)b * 33 + t) * 128 + d] = run;
  }
}

// ---------------- attention kernel ----------------

DEVI void stage_tiles(char* ldsK, char* ldsV, const unsigned short* Kb,
                      const unsigned short* Vt, int b, int kt, int w, int lane) {
  const int kv0 = kt * 64;
  if (w < 2) {
    // K tile: 64 rows x 256B, contiguous in global; XOR-swizzle via pre-swizzled source
    const char* ktile = (const char*)(Kb + ((size_t)b * S_LEN + kv0) * D_DIM);
#pragma unroll
    for (int i = 0; i < 8; i++) {
      int c = w * 8 + i;
      int L = c * 1024 + lane * 16;
      int row = L >> 8;
      int src = row * 256 + ((L & 255) ^ ((row & 7) << 4));
      __builtin_amdgcn_global_load_lds(
          (const __attribute__((address_space(1))) unsigned int*)(ktile + src),
          (__attribute__((address_space(3))) unsigned int*)(ldsK + c * 1024),
          16, 0, 0);
    }
  } else {
    // V^T tile: 128 rows x 128B, row stride S*2 in global
#pragma unroll
    for (int i = 0; i < 8; i++) {
      int c = (w - 2) * 8 + i;
      int L = c * 1024 + lane * 16;
      int row = L >> 7;
      int xs = (L & 127) ^ ((row & 7) << 4);
      const char* src = (const char*)Vt +
                        (((size_t)b * D_DIM + row) * S_LEN + kv0) * 2 + xs;
      __builtin_amdgcn_global_load_lds(
          (const __attribute__((address_space(1))) unsigned int*)src,
          (__attribute__((address_space(3))) unsigned int*)(ldsV + c * 1024),
          16, 0, 0);
    }
  }
}

DEVI short8 ldK(const char* ldsK, int row, int off) {
  int addr = row * 256 + (off ^ ((row & 7) << 4));
  return *reinterpret_cast<const short8*>(ldsK + addr);
}
DEVI short8 ldV(const char* ldsV, int row, int off) {
  int addr = row * 128 + (off ^ ((row & 7) << 4));
  return *reinterpret_cast<const short8*>(ldsV + addr);
}

template <bool MASK>
DEVI void tile_body(const char* cb, const short8* qf, f32x16 (&acc)[4],
                    float& m_run, float& l_run, const int ln31, const int h,
                    const int kh, const int qrow, const int kvb) {
  // S^T = K_half * Q^T  (swapped operands: lane owns one q column)
  f32x16 sT;
#pragma unroll
  for (int r = 0; r < 16; r++) sT[r] = 0.0f;
#pragma unroll
  for (int kf = 0; kf < 8; kf++) {
    short8 af = ldK(cb, ln31 + 32 * kh, 32 * kf + 16 * h);
    sT = __builtin_amdgcn_mfma_f32_32x32x16_bf16(af, qf[kf], sT, 0, 0, 0);
  }
  if (MASK) {
    // multiplicative mask: score := 0 above diagonal (only the diag tile pays this)
#pragma unroll
    for (int r = 0; r < 16; r++) {
      int kvg = kvb + (r & 3) + 8 * (r >> 2) + 4 * h;
      if (kvg > qrow) sT[r] = 0.0f;
    }
  }
  // row max: in-lane tree + one cross-half exchange
  float tm[8];
#pragma unroll
  for (int r = 0; r < 8; r++) tm[r] = fmaxf(sT[r], sT[r + 8]);
#pragma unroll
  for (int r = 0; r < 4; r++) tm[r] = fmaxf(tm[r], tm[r + 4]);
  float mx = fmaxf(fmaxf(tm[0], tm[2]), fmaxf(tm[1], tm[3]));
  mx = fmaxf(mx, __shfl_xor(mx, 32));
  // defer-max: only rescale when some row's max grew past m_run + 8 (P <= 2^8)
  if (!__all(mx <= m_run + 8.0f)) {
    float mnew = fmaxf(m_run, mx);
    float alpha = EXP2(m_run - mnew);
    m_run = mnew;
    l_run *= alpha;
    float ar[16];
#pragma unroll
    for (int r = 0; r < 16; r++)
      ar[r] = __shfl(alpha, (r & 3) + 8 * (r >> 2) + 4 * h);
#pragma unroll
    for (int nt = 0; nt < 4; nt++)
#pragma unroll
      for (int r = 0; r < 16; r++) acc[nt][r] *= ar[r];
  }
#pragma unroll
  for (int r = 0; r < 16; r++) sT[r] = EXP2(sT[r] - m_run);
  float ts[8];
#pragma unroll
  for (int r = 0; r < 8; r++) ts[r] = sT[r] + sT[r + 8];
#pragma unroll
  for (int r = 0; r < 4; r++) ts[r] = ts[r] + ts[r + 4];
  float sum = (ts[0] + ts[1]) + (ts[2] + ts[3]);
  sum += __shfl_xor(sum, 32);
  l_run += sum;
  // pack P -> bf16 A-fragments (v_cvt_pk + cross-half exchange), then PV
#pragma unroll
  for (int kl = 0; kl < 2; kl++) {
    const int ra = 4 * (2 * kl);      // rows local to h=0
    const int rb = 4 * (2 * kl + 1);  // rows local to h=1
    unsigned int ua0 = cvtpk(sT[ra + 0], sT[ra + 1]);
    unsigned int ua1 = cvtpk(sT[ra + 2], sT[ra + 3]);
    unsigned int ub0 = cvtpk(sT[rb + 0], sT[rb + 1]);
    unsigned int ub1 = cvtpk(sT[rb + 2], sT[rb + 3]);
    unsigned int uloc0 = h ? ub0 : ua0, uloc1 = h ? ub1 : ua1;
    unsigned int usnd0 = h ? ua0 : ub0, usnd1 = h ? ua1 : ub1;
    unsigned int urcv0 = (unsigned int)__shfl_xor((int)usnd0, 32);
    unsigned int urcv1 = (unsigned int)__shfl_xor((int)usnd1, 32);
    union { short8 v; unsigned int u[4]; } pa;
    pa.u[0] = h ? urcv0 : uloc0;
    pa.u[1] = h ? urcv1 : uloc1;
    pa.u[2] = h ? uloc0 : urcv0;
    pa.u[3] = h ? uloc1 : urcv1;
    const int vboff = 64 * kh + 32 * kl + 16 * h;
#pragma unroll
    for (int nt = 0; nt < 4; nt++) {
      short8 vb = ldV(cb + 16384, ln31 + 32 * nt, vboff);
      acc[nt] = __builtin_amdgcn_mfma_f32_32x32x16_bf16(pa.v, vb, acc[nt], 0, 0, 0);
    }
  }
}

__global__ __launch_bounds__(256, 2) void attn_kernel(
    const float* __restrict__ Q, const unsigned short* __restrict__ Kb,
    const unsigned short* __restrict__ Vt, const float* __restrict__ SufV,
    float* __restrict__ out) {
  __shared__ __align__(16) char smem[2][32768];  // per buf: K tile @0 (16KB), V^T tile @16KB

  const int tid = threadIdx.x;
  const int w = tid >> 6, lane = tid & 63;
  const int ln31 = lane & 31, h = lane >> 5;
  const int qs = w & 1;   // q half: rows [q0+32*qs, +32)
  const int kh = w >> 1;  // kv half of each 64-tile

  // dispatch swizzle: XCD-local batches + (j, 31-j) CU pairing
  const int bid = blockIdx.x;
  const int x = bid & 7, s = bid >> 3;
  const int b = 2 * x + (s & 1);
  const int sh = s >> 1;
  const int j = (s < 32) ? sh : (47 - sh);
  const int q0 = j * 64;
  const int kv_end = q0 + 64;
  const int qrow = q0 + 32 * qs + ln31;

  // Q fragments (B-operand) from fp32, scale*log2e folded in:
  // frag kf element jj <-> d = 16*kf + 8*h + jj
  short8 qf[8];
  {
    const float* qsrc = Q + ((size_t)b * S_LEN + qrow) * D_DIM + 8 * h;
#pragma unroll
    for (int kf = 0; kf < 8; kf++) {
      float4 a = *reinterpret_cast<const float4*>(qsrc + 16 * kf);
      float4 c = *reinterpret_cast<const float4*>(qsrc + 16 * kf + 4);
      union { short8 v; unsigned int u[4]; } q8;
      q8.u[0] = cvtpk(a.x * QSC, a.y * QSC);
      q8.u[1] = cvtpk(a.z * QSC, a.w * QSC);
      q8.u[2] = cvtpk(c.x * QSC, c.y * QSC);
      q8.u[3] = cvtpk(c.z * QSC, c.w * QSC);
      qf[kf] = q8.v;
    }
  }

  f32x16 acc[4];
#pragma unroll
  for (int nt = 0; nt < 4; nt++)
#pragma unroll
    for (int r = 0; r < 16; r++) acc[nt][r] = 0.0f;

  float m_run = 0.0f, l_run = 0.0f;  // m starts at 0: masked zeros are in the softmax

  stage_tiles(smem[0], smem[0] + 16384, Kb, Vt, b, 0, w, lane);
  __syncthreads();

  for (int kt = 0; kt < j; kt++) {  // all-unmasked tiles
    char* cb = smem[kt & 1];
    stage_tiles(smem[(kt + 1) & 1], smem[(kt + 1) & 1] + 16384, Kb, Vt, b,
                kt + 1, w, lane);
    tile_body<false>(cb, qf, acc, m_run, l_run, ln31, h, kh, qrow,
                     kt * 64 + 32 * kh);
    __syncthreads();
  }
  // diagonal tile (masked)
  tile_body<true>(smem[j & 1], qf, acc, m_run, l_run, ln31, h, kh, qrow,
                  j * 64 + 32 * kh);
  __syncthreads();

  // merge kv halves (disjoint key sets) + masked-tail correction + write
  float* mb = (float*)smem;  // [2][64][69] floats, reuses tile LDS (stride 69: bank-conflict-free)
  if (kh == 1) {
    float* p = mb + (size_t)(qs * 64 + lane) * 69;
#pragma unroll
    for (int nt = 0; nt < 4; nt++)
#pragma unroll
      for (int r = 0; r < 16; r++) p[nt * 16 + r] = acc[nt][r];
    p[64] = m_run;
    p[65] = l_run;
  }
  __syncthreads();
  if (kh == 0) {
    const float* p = mb + (size_t)(qs * 64 + lane) * 69;
    float m1 = p[64], l1 = p[65];
    float m12 = fmaxf(m_run, m1);
    float b0 = EXP2(m_run - m12);
    float b1 = EXP2(m1 - m12);
    float l12 = l_run * b0 + l1 * b1;
    float e = EXP2(-m12);  // weight of each fully-masked (score 0) position
    l12 += (float)(S_LEN - kv_end) * e;
    float b0r[16], b1r[16], er[16], lr[16];
#pragma unroll
    for (int r = 0; r < 16; r++) {
      int cr = (r & 3) + 8 * (r >> 2) + 4 * h;
      b0r[r] = __shfl(b0, cr);
      b1r[r] = __shfl(b1, cr);
      er[r] = __shfl(e, cr);
      lr[r] = __shfl(l12, cr);
    }
    const float* sv = SufV + ((size_t)b * 33 + (kv_end >> 6)) * 128;
    float* ob = out + ((size_t)b * S_LEN + q0 + 32 * qs) * D_DIM + ln31;
#pragma unroll
    for (int nt = 0; nt < 4; nt++) {
      float svv = sv[ln31 + 32 * nt];
#pragma unroll
      for (int r = 0; r < 16; r++) {
        int cr = (r & 3) + 8 * (r >> 2) + 4 * h;
        float o = acc[nt][r] * b0r[r] + p[nt * 16 + r] * b1r[r] + er[r] * svv;
        ob[(size_t)cr * D_DIM + 32 * nt] = o / lr[r];
      }
    }
  }
}

// ---------------- launcher ----------------

extern "C" void kernel_launch(void* const* d_in, const int* in_sizes, int n_in,
                              void* d_out, int out_size, void* d_ws, size_t ws_size,
                              hipStream_t stream) {
  const float* Q = (const float*)d_in[0];
  const float* K = (const float*)d_in[1];
  const float* V = (const float*)d_in[2];
  float* out = (float*)d_out;

  char* ws = (char*)d_ws;
  unsigned short* Kb = (unsigned short*)ws;                 // 8 MiB
  unsigned short* Vt = Kb + 4194304;                        // 8 MiB
  float* Tsum = (float*)(ws + 16777216);                    // 256 KiB
  float* SufV = Tsum + 65536;                               // 264 KiB

  cvtk<<<2048, 256, 0, stream>>>(K, Kb);
  vtrans<<<1024, 256, 0, stream>>>(V, Vt, Tsum);
  sufB<<<16, 128, 0, stream>>>(Tsum, SufV);
  attn_kernel<<<512, 256, 0, stream>>>(Q, Kb, Vt, SufV, out);
}